// Round 16
// baseline (572.493 us; speedup 1.0000x reference)
//
#include <hip/hip_runtime.h>
#include <hip/hip_bf16.h>

typedef _Float16 half8 __attribute__((ext_vector_type(8)));
typedef _Float16 half2t __attribute__((ext_vector_type(2)));
typedef float f32x4 __attribute__((ext_vector_type(4)));

#define B_SZ 64
#define T_SZ 512
#define E_SZ 768
#define H_SZ 256
#define V_SZ 3072

// workspace layout (bytes)
#define WS_X     0u          // _Float16 x[T][B][H]           16,777,216 B
#define WS_WT    16777216u   // _Float16 Wt[256][768] (Wxh^T)    393,216 B
#define WS_WF    17170432u   // _Float16 Wf[65536] Whh MFMA-B    131,072 B
#define WS_WP    17301504u   // uint     Wp[256][128] ([j][k])   131,072 B
#define WS_H     17432576u   // float    h[64][256]               65,536 B

static __device__ __forceinline__ float dot2p(int hp, unsigned int wp, float c) {
  return __builtin_amdgcn_fdot2(__builtin_bit_cast(half2t, hp),
                                __builtin_bit_cast(half2t, wp), c, false);
}

// fast tanh: 1 - 2/(1+exp(2x)); exact at +/-inf, ~1e-6 rel err
static __device__ __forceinline__ float fast_tanh(float x) {
  float e = __builtin_amdgcn_exp2f(x * 2.8853900817779268f); // exp(2x)
  return 1.0f - 2.0f * __builtin_amdgcn_rcpf(1.0f + e);
}

// ---------------- k0: prep f16 weight layouts (small) ----------------
// Wt[h][e] = Wxh[e][h] (k1 B panels).
// Wf = Whh in 16x16x32 MFMA-B fragment order (r7-validated).
// Wp[j][k] = packed f16 pair (Whh[2k][j], Whh[2k+1][j]) for the dot2 path.
__global__ __launch_bounds__(256) void k0_convert(
    const float* __restrict__ Wxh,
    const float* __restrict__ Whh,
    _Float16* __restrict__ Wt,
    _Float16* __restrict__ Wf,
    unsigned int* __restrict__ Wp)
{
  int gid = blockIdx.x * 256 + threadIdx.x;           // 768 WGs = 196608
  if (gid < E_SZ * H_SZ) {
    int e = gid >> 8, h = gid & 255;
    Wt[h * E_SZ + e] = (_Float16)Wxh[gid];
  }
  if (gid < 65536) {
    int j = gid & 7, lane = (gid >> 3) & 63, kt = (gid >> 9) & 7, nt = gid >> 12;
    int quad = lane >> 4, n16 = lane & 15;
    int row = kt * 32 + quad * 8 + j, col = nt * 16 + n16;
    Wf[gid] = (_Float16)Whh[row * H_SZ + col];
  }
  if (gid < 32768) {                                  // pack pairs, layout [j][k]
    int j = gid >> 7, k = gid & 127;
    _Float16 lo = (_Float16)Whh[(2 * k) * H_SZ + j];
    _Float16 hi = (_Float16)Whh[(2 * k + 1) * H_SZ + j];
    unsigned short lu = __builtin_bit_cast(unsigned short, lo);
    unsigned short hu = __builtin_bit_cast(unsigned short, hi);
    Wp[j * 128 + k] = (unsigned int)lu | ((unsigned int)hu << 16);
  }
}

// ---------------- k1: x[t,b,:] = emb[idx[b,t],:] @ Wxh  (MFMA f16) ----------------
__global__ __launch_bounds__(256) void k1_xproj(
    const int* __restrict__ idx,
    const float* __restrict__ emb,
    const _Float16* __restrict__ Wt,
    _Float16* __restrict__ x)
{
  const int tid  = threadIdx.x;
  const int w    = tid >> 6;
  const int lane = tid & 63;
  const int m16  = lane & 15;
  const int quad = lane >> 4;
  const int r = blockIdx.x * 64 + w * 16 + m16;     // row in [T*B], r = t*64 + b
  const int t = r >> 6;
  const int b = r & 63;
  const int erow = idx[b * T_SZ + t];
  const float* Arow = emb + (size_t)erow * E_SZ + quad * 8;   // A[m][k=quad*8+j]

  __shared__ __align__(16) _Float16 bp[2][16 * 64 * 8]; // 2 x 16KB fragment panels
  int n_[4], kb_[4];
#pragma unroll
  for (int pp = 0; pp < 4; ++pp) {
    int f = tid + 256 * pp;
    n_[pp]  = ((f >> 6) << 4) | (f & 15);
    kb_[pp] = (f >> 4) & 3;
  }
  uint4 stg[4];
#pragma unroll
  for (int pp = 0; pp < 4; ++pp)
    stg[pp] = *(const uint4*)(Wt + (size_t)n_[pp] * E_SZ + kb_[pp] * 8);
  f32x4 af0 = *(const f32x4*)(Arow);
  f32x4 af1 = *(const f32x4*)(Arow + 4);

  f32x4 acc[16];
#pragma unroll
  for (int n = 0; n < 16; ++n) { f32x4 z = {0.f, 0.f, 0.f, 0.f}; acc[n] = z; }

#pragma unroll
  for (int pp = 0; pp < 4; ++pp)
    *(uint4*)(bp[0] + (size_t)(tid + 256 * pp) * 8) = stg[pp];
  __syncthreads();

#pragma unroll 1
  for (int ki = 0; ki < 24; ++ki) {
    const _Float16* cur = bp[ki & 1];
    f32x4 af0n = af0, af1n = af1;
    if (ki < 23) {
#pragma unroll
      for (int pp = 0; pp < 4; ++pp)
        stg[pp] = *(const uint4*)(Wt + (size_t)n_[pp] * E_SZ + (ki + 1) * 32 + kb_[pp] * 8);
      af0n = *(const f32x4*)(Arow + (ki + 1) * 32);
      af1n = *(const f32x4*)(Arow + (ki + 1) * 32 + 4);
    }
    half8 a;
#pragma unroll
    for (int e = 0; e < 4; ++e) { a[e] = (_Float16)af0[e]; a[4 + e] = (_Float16)af1[e]; }
#pragma unroll
    for (int nt = 0; nt < 16; ++nt) {
      half8 bb = *(const half8*)(cur + (size_t)(nt * 64 + lane) * 8);
      acc[nt] = __builtin_amdgcn_mfma_f32_16x16x32_f16(a, bb, acc[nt], 0, 0, 0);
    }
    if (ki < 23) {
#pragma unroll
      for (int pp = 0; pp < 4; ++pp)
        *(uint4*)(bp[(ki + 1) & 1] + (size_t)(tid + 256 * pp) * 8) = stg[pp];
      __syncthreads();
    }
    af0 = af0n; af1 = af1n;
  }
  const int rbase = blockIdx.x * 64 + w * 16 + quad * 4;  // C/D: col=lane&15, row=quad*4+reg
#pragma unroll
  for (int nt = 0; nt < 16; ++nt) {
    const int col = nt * 16 + m16;
#pragma unroll
    for (int rg = 0; rg < 4; ++rg) {
      x[(size_t)(rbase + rg) * H_SZ + col] = (_Float16)acc[nt][rg];
    }
  }
}

// ---------------- k2: hybrid MFMA + dot2 recurrence, 8 waves ----------------
// Wave w covers cols [32w,32w+32): cols [32w,32w+16) via ONE MFMA N-tile
// (8 chained MFMAs, B in a0..a31) and cols [32w+16,32w+32) via v_dot2 with
// weights parked in a32..a63 (4 lanes/col over K-quarters, quad-reduced by
// shfl_xor). MFMA pipe load halves to ~310 cyc/SIMD; the dot2 VALU work runs
// CONCURRENTLY on the VALU pipe (m114) instead of idling during MFMA bursts.
#define LDFRAG(KT, R0, R1, R2, R3) { \
  uint4 q = Wf4[(((size_t)(2 * w) * 8 + KT) * 64) + lane]; \
  asm volatile("v_accvgpr_write_b32 a" #R0 ", %0" :: "v"(q.x) : "a" #R0); \
  asm volatile("v_accvgpr_write_b32 a" #R1 ", %0" :: "v"(q.y) : "a" #R1); \
  asm volatile("v_accvgpr_write_b32 a" #R2 ", %0" :: "v"(q.z) : "a" #R2); \
  asm volatile("v_accvgpr_write_b32 a" #R3 ", %0" :: "v"(q.w) : "a" #R3); }

#define PARKD(I, R0, R1, R2, R3) { \
  uint4 p = WpC[I]; \
  asm volatile("v_accvgpr_write_b32 a" #R0 ", %0" :: "v"(p.x) : "a" #R0); \
  asm volatile("v_accvgpr_write_b32 a" #R1 ", %0" :: "v"(p.y) : "a" #R1); \
  asm volatile("v_accvgpr_write_b32 a" #R2 ", %0" :: "v"(p.z) : "a" #R2); \
  asm volatile("v_accvgpr_write_b32 a" #R3 ", %0" :: "v"(p.w) : "a" #R3); }

#define MFMA_K0(A0) \
  asm volatile("v_mfma_f32_16x16x32_f16 %[t0], %[a], a[0:3], %[z]" \
    : [t0] "=&v"(accm) : [a] "v"(A0), [z] "v"(zero4));
#define MFMA_KT(A0, B) \
  asm volatile("v_mfma_f32_16x16x32_f16 %[t0], %[a], a[" #B "], %[t0]" \
    : [t0] "+v"(accm) : [a] "v"(A0));
#define MFMA_K7(A0, B) \
  asm volatile("v_mfma_f32_16x16x32_f16 %[t0], %[a], a[" #B "], %[t0]\n\t" \
    "s_nop 7\n\ts_nop 7" : [t0] "+v"(accm) : [a] "v"(A0));

#define DOT4(HV, R0, R1, R2, R3) { \
  unsigned w0_, w1_, w2_, w3_; \
  asm volatile("v_accvgpr_read_b32 %0, a" #R0 : "=v"(w0_)); \
  asm volatile("v_accvgpr_read_b32 %0, a" #R1 : "=v"(w1_)); \
  asm volatile("v_accvgpr_read_b32 %0, a" #R2 : "=v"(w2_)); \
  asm volatile("v_accvgpr_read_b32 %0, a" #R3 : "=v"(w3_)); \
  s0 = dot2p((int)HV.x, w0_, s0); s1 = dot2p((int)HV.y, w1_, s1); \
  s2 = dot2p((int)HV.z, w2_, s2); s3 = dot2p((int)HV.w, w3_, s3); }

__global__ __launch_bounds__(512) void k2_rnn(
    const _Float16* __restrict__ Wf,
    const unsigned int* __restrict__ Wp,
    const _Float16* __restrict__ x,
    const float* __restrict__ Bh,
    float* __restrict__ hout,
    float* __restrict__ hidout)
{
  const int b    = blockIdx.x;
  const int tid  = threadIdx.x;
  const int w    = tid >> 6;          // wave 0..7
  const int lane = tid & 63;
  const int quad = lane >> 4;
  const int n16  = lane & 15;
  __shared__ __align__(16) _Float16 hb[2][H_SZ];
  const uint4* Wf4 = (const uint4*)Wf;
  const uint4* Wp4 = (const uint4*)Wp;

  // MFMA B-frags: N-tile 2w, kt=0..7 -> a0..a31
  LDFRAG(0,  0,  1,  2,  3)  LDFRAG(1,  4,  5,  6,  7)
  LDFRAG(2,  8,  9, 10, 11)  LDFRAG(3, 12, 13, 14, 15)
  LDFRAG(4, 16, 17, 18, 19)  LDFRAG(5, 20, 21, 22, 23)
  LDFRAG(6, 24, 25, 26, 27)  LDFRAG(7, 28, 29, 30, 31)
  // dot2 weights: col cd = 32w+16+n16, K-quarter quad -> pairs [32q,32q+32)
  const int cd = w * 32 + 16 + n16;
  const uint4* WpC = Wp4 + ((size_t)cd * 32 + quad * 8);
  PARKD(0, 32, 33, 34, 35)  PARKD(1, 36, 37, 38, 39)
  PARKD(2, 40, 41, 42, 43)  PARKD(3, 44, 45, 46, 47)
  PARKD(4, 48, 49, 50, 51)  PARKD(5, 52, 53, 54, 55)
  PARKD(6, 56, 57, 58, 59)  PARKD(7, 60, 61, 62, 63)

  const int cm = w * 32 + n16;              // MFMA col
  const float bh0 = Bh[cm];
  const float bh1 = Bh[cd];
  const _Float16* xp0 = x + b * H_SZ + cm;
  const _Float16* xp1 = x + b * H_SZ + cd;
  _Float16 xq0 = xp0[0], xq1 = xp1[0];
  f32x4 zero4 = {0.f, 0.f, 0.f, 0.f};
  asm volatile("" : "+v"(zero4));
  if (tid < H_SZ) hb[1][tid] = (_Float16)0.f;
  float h0 = 0.f, h1 = 0.f;
  __syncthreads();

#pragma unroll 1
  for (int t = 0; t < T_SZ; ++t) {
    const int tn = (t < T_SZ - 1) ? (t + 1) : t;
    _Float16 xn0 = xp0[(size_t)tn * (B_SZ * H_SZ)];
    _Float16 xn1 = xp1[(size_t)tn * (B_SZ * H_SZ)];
    const _Float16* hr = hb[(t + 1) & 1];
    // MFMA A-frags (quad-broadcast, static offsets)
    half8 va0 = *(const half8*)(hr +   0 + quad * 8);
    half8 va1 = *(const half8*)(hr +  32 + quad * 8);
    half8 va2 = *(const half8*)(hr +  64 + quad * 8);
    half8 va3 = *(const half8*)(hr +  96 + quad * 8);
    half8 va4 = *(const half8*)(hr + 128 + quad * 8);
    half8 va5 = *(const half8*)(hr + 160 + quad * 8);
    half8 va6 = *(const half8*)(hr + 192 + quad * 8);
    half8 va7 = *(const half8*)(hr + 224 + quad * 8);
    // dot2 h pairs: quarter quad = f16[64q .. 64q+64) = 8 uint4 (broadcast)
    const uint4* hq = (const uint4*)(hr + quad * 64);
    uint4 hv0 = hq[0], hv1 = hq[1], hv2 = hq[2], hv3 = hq[3];
    uint4 hv4 = hq[4], hv5 = hq[5], hv6 = hq[6], hv7 = hq[7];

    f32x4 accm;
    float s0 = 0.f, s1 = 0.f, s2 = 0.f, s3 = 0.f;
    MFMA_K0(va0)
    DOT4(hv0, 32, 33, 34, 35)
    MFMA_KT(va1,  4:7)
    DOT4(hv1, 36, 37, 38, 39)
    MFMA_KT(va2,  8:11)
    DOT4(hv2, 40, 41, 42, 43)
    MFMA_KT(va3, 12:15)
    DOT4(hv3, 44, 45, 46, 47)
    MFMA_KT(va4, 16:19)
    DOT4(hv4, 48, 49, 50, 51)
    MFMA_KT(va5, 20:23)
    DOT4(hv5, 52, 53, 54, 55)
    MFMA_KT(va6, 24:27)
    DOT4(hv6, 56, 57, 58, 59)
    MFMA_K7(va7, 28:31)
    DOT4(hv7, 60, 61, 62, 63)
    // dot2 col: reduce 4 chains, then across the 4 K-quarters (quads)
    float yd = (s0 + s1) + (s2 + s3);
    yd += __shfl_xor(yd, 16, 64);
    yd += __shfl_xor(yd, 32, 64);
    // MFMA col: rows replicated -> acc[0] valid in every lane
    h0 = fast_tanh(accm[0] + (float)xq0 + bh0);
    h1 = fast_tanh(yd + (float)xq1 + bh1);
    if (quad == 0) {
      hb[t & 1][cm] = (_Float16)h0;
      hb[t & 1][cd] = (_Float16)h1;
    }
    __syncthreads();
    xq0 = xn0; xq1 = xn1;
  }
  if (quad == 0) {
    hout[b * H_SZ + cm] = h0;  hout[b * H_SZ + cd] = h1;
    hidout[b * H_SZ + cm] = h0; hidout[b * H_SZ + cd] = h1;
  }
}

// ---------------- k3: out = hidden @ Wy + By  (all f32) ----------------
__global__ __launch_bounds__(256) void k3_out(
    const float* __restrict__ h,
    const float* __restrict__ Wy,
    const float* __restrict__ By,
    float* __restrict__ out)
{
  __shared__ float hs[H_SZ];
  const int c = blockIdx.x;   // vocab chunk
  const int b = blockIdx.y;   // batch
  const int v = c * 256 + threadIdx.x;
  hs[threadIdx.x] = h[b * H_SZ + threadIdx.x];
  __syncthreads();
  float acc = By[v];
#pragma unroll 8
  for (int jj = 0; jj < H_SZ; ++jj) {
    acc += hs[jj] * Wy[(size_t)jj * V_SZ + v];
  }
  out[(size_t)b * V_SZ + v] = acc;
}

extern "C" void kernel_launch(void* const* d_in, const int* in_sizes, int n_in,
                              void* d_out, int out_size, void* d_ws, size_t ws_size,
                              hipStream_t stream)
{
  const int*   idx = (const int*)d_in[0];
  const float* emb = (const float*)d_in[1];
  const float* Wxh = (const float*)d_in[2];
  const float* Whh = (const float*)d_in[3];
  const float* Wy  = (const float*)d_in[4];
  const float* By  = (const float*)d_in[5];
  const float* Bh  = (const float*)d_in[6];

  char* ws = (char*)d_ws;
  _Float16*     x    = (_Float16*)(ws + WS_X);
  _Float16*     Wt   = (_Float16*)(ws + WS_WT);
  _Float16*     Wf   = (_Float16*)(ws + WS_WF);
  unsigned int* Wp   = (unsigned int*)(ws + WS_WP);
  float*        hbuf = (float*)(ws + WS_H);

  float* out    = (float*)d_out;
  float* hidout = out + (size_t)B_SZ * V_SZ;

  k0_convert<<<768, 256, 0, stream>>>(Wxh, Whh, Wt, Wf, Wp);
  k1_xproj  <<<512, 256, 0, stream>>>(idx, emb, Wt, x);
  k2_rnn    <<<64, 512, 0, stream>>>(Wf, Wp, x, Bh, hbuf, hidout);
  k3_out    <<<dim3(12, 64), 256, 0, stream>>>(hbuf, Wy, By, out);
}